// Round 6
// baseline (7164.820 us; speedup 1.0000x reference)
//
#include <hip/hip_runtime.h>
#include <hip/hip_bf16.h>

#define BB 4
#define LL 2048
#define DMODEL 2048
#define DSTATE 64
#define DCONV 4
#define DINNER 4096
#define NHEADS 64
#define CONVDIM 4224   // DINNER + 2*DSTATE
#define DINPROJ 8384   // 2*DINNER + 2*DSTATE + NHEADS
#define MROWS 8192     // BB*LL
#define DTROW0 8320    // 2*DINNER + 2*DSTATE : first dt row of in_proj_w

__device__ inline unsigned short f2bf(float f) {
  unsigned int u = __float_as_uint(f);
  u += 0x7FFF + ((u >> 16) & 1);   // RNE
  return (unsigned short)(u >> 16);
}
__device__ inline float bf2f(unsigned short u) {
  return __uint_as_float(((unsigned int)u) << 16);
}

// ---------------- fp32 tiled GEMM: C[M,N] = A[M,K] * B[N,K]^T ----------------
// 128x128 tile, BK=8, 256 threads, 8x8 outputs/thread. Simple & verifiable.
// A may be fp32 (ABF16=false) or bf16 (ABF16=true). B is fp32. M % 128 == 0.
template <bool ABF16, bool BF16OUT>
__global__ void gemm_tiled(const void* __restrict__ Av,
                           const float* __restrict__ B,
                           void* __restrict__ Cv, int M, int N, int K) {
  __shared__ float sA[8][128];
  __shared__ float sB[8][132];
  const int tid = threadIdx.x;
  const int tx = tid & 15, ty = tid >> 4;
  const long m_base = (long)blockIdx.y * 128;
  const long n_base = (long)blockIdx.x * 128;
  const float* Af = (const float*)Av;
  const unsigned short* Ab = (const unsigned short*)Av;

  float acc[8][8] = {};

  for (int k0 = 0; k0 < K; k0 += 8) {
    __syncthreads();
#pragma unroll
    for (int u = 0; u < 4; ++u) {
      int idx = u * 256 + tid;          // 0..1023
      int kk = idx & 7, mm = idx >> 3;  // kk 0..7, mm 0..127
      long gm = m_base + mm;            // M is a multiple of 128
      sA[kk][mm] = ABF16 ? bf2f(Ab[gm * K + k0 + kk]) : Af[gm * K + k0 + kk];
      long gn = n_base + mm; if (gn >= N) gn = N - 1;   // clamp; stores guarded
      sB[kk][mm] = B[gn * K + k0 + kk];
    }
    __syncthreads();
#pragma unroll
    for (int kk = 0; kk < 8; ++kk) {
      float av[8], bv[8];
#pragma unroll
      for (int i = 0; i < 8; ++i) av[i] = sA[kk][ty + i * 16];
#pragma unroll
      for (int j = 0; j < 8; ++j) bv[j] = sB[kk][tx + j * 16];
#pragma unroll
      for (int i = 0; i < 8; ++i)
#pragma unroll
        for (int j = 0; j < 8; ++j)
          acc[i][j] += av[i] * bv[j];
    }
  }

#pragma unroll
  for (int i = 0; i < 8; ++i) {
    const long mrow = m_base + ty + i * 16;
#pragma unroll
    for (int j = 0; j < 8; ++j) {
      const long ncol = n_base + tx + j * 16;
      if (ncol < N) {
        if (BF16OUT) ((unsigned short*)Cv)[mrow * N + ncol] = f2bf(acc[i][j]);
        else         ((float*)Cv)[mrow * N + ncol] = acc[i][j];
      }
    }
  }
}

// ---------------- fp32 dt path: dt_raw = x @ w_dt^T, softplus, dA ----------------
__global__ void dt_kernel(const float* __restrict__ x,
                          const float* __restrict__ w,     // in_proj_w (full)
                          const float* __restrict__ dt_bias,
                          const float* __restrict__ A_log,
                          float* __restrict__ dtv, float* __restrict__ dAv) {
  __shared__ float s_w[64][129];
  __shared__ float s_x[16][129];
  const int tid = threadIdx.x;
  const int row0 = blockIdx.x * 16;
  const int c = tid & 63;        // head
  const int rg = tid >> 6;       // 0..3 -> rows rg*4..rg*4+3
  float acc[4] = {0.f, 0.f, 0.f, 0.f};
  for (int k0 = 0; k0 < DMODEL; k0 += 128) {
    __syncthreads();
#pragma unroll
    for (int u = 0; u < 32; ++u) {   // 64*128/256
      int idx = u * 256 + tid;
      int r = idx >> 7, kk = idx & 127;
      s_w[r][kk] = w[(size_t)(DTROW0 + r) * DMODEL + k0 + kk];
    }
#pragma unroll
    for (int u = 0; u < 8; ++u) {    // 16*128/256
      int idx = u * 256 + tid;
      int r = idx >> 7, kk = idx & 127;
      s_x[r][kk] = x[(size_t)(row0 + r) * DMODEL + k0 + kk];
    }
    __syncthreads();
    for (int kk = 0; kk < 128; ++kk) {
      float wv = s_w[c][kk];
#pragma unroll
      for (int j = 0; j < 4; ++j) acc[j] += s_x[rg * 4 + j][kk] * wv;
    }
  }
  const float a = expf(A_log[c]);
  const float bias = dt_bias[c];
#pragma unroll
  for (int j = 0; j < 4; ++j) {
    int row = row0 + rg * 4 + j;
    float v = acc[j] + bias;
    float dt = (v > 20.f) ? v : log1pf(expf(v));   // softplus
    dtv[(size_t)row * 64 + c] = dt;
    dAv[(size_t)row * 64 + c] = expf(-dt * a);
  }
}

// ---------------- conv(4) + silu ----------------
__global__ void conv_kernel(const unsigned short* __restrict__ zxb,
                            const float* __restrict__ conv_w,
                            const float* __restrict__ conv_b,
                            unsigned short* __restrict__ xh,
                            float* __restrict__ Bm,
                            float* __restrict__ Cm) {
  const int row = blockIdx.x;          // b*LL + l
  const int l = row & (LL - 1);
  for (int c = threadIdx.x; c < CONVDIM; c += 256) {
    float acc = conv_b[c];
#pragma unroll
    for (int k = 0; k < DCONV; ++k) {
      int ll = l - (DCONV - 1) + k;
      if (ll >= 0) {
        size_t rr = (size_t)row + (ll - l);
        acc += bf2f(zxb[rr * DINPROJ + DINNER + c]) * conv_w[c * DCONV + k];
      }
    }
    float s = acc / (1.f + expf(-acc));   // silu
    if (c < DINNER)               xh[(size_t)row * DINNER + c] = f2bf(s);
    else if (c < DINNER + DSTATE) Bm[(size_t)row * DSTATE + (c - DINNER)] = s;
    else                          Cm[(size_t)row * DSTATE + (c - DINNER - DSTATE)] = s;
  }
}

// ---------------- sequential selective scan ----------------
#define CT 16
__global__ void scan_kernel(const unsigned short* xh,      // NOT restrict: y aliases xh
                            const float* __restrict__ Bm,
                            const float* __restrict__ Cm,
                            const float* __restrict__ dtv,
                            const float* __restrict__ dAv,
                            const float* __restrict__ Dv,
                            unsigned short* y) {
  __shared__ __align__(16) float s_x[CT][64];
  __shared__ __align__(16) float s_B[CT][64];
  __shared__ __align__(16) float s_C[CT][64];
  __shared__ __align__(16) float s_y[CT][64];
  __shared__ float s_dt[CT], s_dA[CT];
  const int b = blockIdx.x >> 6;
  const int head = blockIdx.x & 63;
  const int tid = threadIdx.x;
  const int p = tid >> 2, q = tid & 3, n0 = q * 16;
  const float Dh = Dv[head];
  float h[16];
#pragma unroll
  for (int i = 0; i < 16; ++i) h[i] = 0.f;

  for (int t0 = 0; t0 < LL; t0 += CT) {
    __syncthreads();   // previous chunk's s_y reads done before overwrite
#pragma unroll
    for (int u = 0; u < CT * 64 / 256; ++u) {
      int idx = u * 256 + tid;
      int tt = idx >> 6, cc = idx & 63;
      size_t r = (size_t)(b * LL + t0 + tt);
      s_x[tt][cc] = bf2f(xh[r * DINNER + head * 64 + cc]);
      s_B[tt][cc] = Bm[r * 64 + cc];
      s_C[tt][cc] = Cm[r * 64 + cc];
    }
    if (tid < CT) {
      size_t r = (size_t)(b * LL + t0 + tid);
      s_dt[tid] = dtv[r * 64 + head];
      s_dA[tid] = dAv[r * 64 + head];
    }
    __syncthreads();
    for (int tt = 0; tt < CT; ++tt) {
      float dA = s_dA[tt], dt = s_dt[tt];
      float xp = s_x[tt][p];
      float dtx = dt * xp;
      const float4* Bp = (const float4*)&s_B[tt][n0];
      const float4* Cp = (const float4*)&s_C[tt][n0];
      float ys = 0.f;
#pragma unroll
      for (int i = 0; i < 4; ++i) {
        float4 bv = Bp[i];
        float4 cv = Cp[i];
        h[4*i+0] = h[4*i+0] * dA + dtx * bv.x;  ys += h[4*i+0] * cv.x;
        h[4*i+1] = h[4*i+1] * dA + dtx * bv.y;  ys += h[4*i+1] * cv.y;
        h[4*i+2] = h[4*i+2] * dA + dtx * bv.z;  ys += h[4*i+2] * cv.z;
        h[4*i+3] = h[4*i+3] * dA + dtx * bv.w;  ys += h[4*i+3] * cv.w;
      }
      ys += __shfl_xor(ys, 1);
      ys += __shfl_xor(ys, 2);
      if (q == 0) s_y[tt][p] = ys + Dh * xp;
    }
    __syncthreads();   // all waves' s_y writes visible before cross-wave reads
#pragma unroll
    for (int u = 0; u < CT * 64 / 256; ++u) {
      int idx = u * 256 + tid;
      int tt = idx >> 6, cc = idx & 63;
      size_t r = (size_t)(b * LL + t0 + tt);
      y[r * DINNER + head * 64 + cc] = f2bf(s_y[tt][cc]);
    }
  }
}

// ---------------- gated RMSNorm (in-place bf16) ----------------
__global__ void norm_kernel(const unsigned short* y,       // NOT restrict: ynb aliases y
                            const unsigned short* __restrict__ zxb,
                            const float* __restrict__ norm_w,
                            unsigned short* ynb) {
  const int row = blockIdx.x;
  const int tid = threadIdx.x;
  float g[16];
  float ss = 0.f;
#pragma unroll
  for (int i = 0; i < 16; ++i) {
    int d = i * 256 + tid;
    float zv = bf2f(zxb[(size_t)row * DINPROJ + d]);
    float gv = bf2f(y[(size_t)row * DINNER + d]) * (zv / (1.f + expf(-zv)));
    g[i] = gv;
    ss += gv * gv;
  }
#pragma unroll
  for (int off = 32; off >= 1; off >>= 1) ss += __shfl_xor(ss, off);
  __shared__ float sred[4];
  __shared__ float s_rs;
  if ((tid & 63) == 0) sred[tid >> 6] = ss;
  __syncthreads();
  if (tid == 0) {
    float tot = sred[0] + sred[1] + sred[2] + sred[3];
    s_rs = rsqrtf(tot / (float)DINNER + 1e-5f);
  }
  __syncthreads();
  float rs = s_rs;
#pragma unroll
  for (int i = 0; i < 16; ++i) {
    int d = i * 256 + tid;
    ynb[(size_t)row * DINNER + d] = f2bf(g[i] * rs * norm_w[d]);
  }
}

// ---------------- classifier head (fp32 out — d_out is float32) ----------------
__global__ void cls_kernel(const float* __restrict__ h,
                           const float* __restrict__ cls_w,
                           const float* __restrict__ cls_b,
                           float* __restrict__ out) {
  const int row = blockIdx.x;
  const int tid = threadIdx.x;
  float a0 = 0, a1 = 0, a2 = 0, a3 = 0;
  for (int d = tid; d < DMODEL; d += 256) {
    float hv = h[(size_t)row * DMODEL + d];
    a0 += hv * cls_w[d];
    a1 += hv * cls_w[DMODEL + d];
    a2 += hv * cls_w[2 * DMODEL + d];
    a3 += hv * cls_w[3 * DMODEL + d];
  }
#pragma unroll
  for (int off = 32; off >= 1; off >>= 1) {
    a0 += __shfl_xor(a0, off); a1 += __shfl_xor(a1, off);
    a2 += __shfl_xor(a2, off); a3 += __shfl_xor(a3, off);
  }
  __shared__ float sred[4][4];
  if ((tid & 63) == 0) { int w = tid >> 6; sred[w][0] = a0; sred[w][1] = a1; sred[w][2] = a2; sred[w][3] = a3; }
  __syncthreads();
  if (tid < 4) {
    float s = sred[0][tid] + sred[1][tid] + sred[2][tid] + sred[3][tid] + cls_b[tid];
    out[(size_t)row * 4 + tid] = s;   // fp32 store: reference output dtype is float32
  }
}

extern "C" void kernel_launch(void* const* d_in, const int* in_sizes, int n_in,
                              void* d_out, int out_size, void* d_ws, size_t ws_size,
                              hipStream_t stream) {
  // Inputs: fp32 storage (bf16-read gives NaN -> proven fp32 layout).
  // Output: fp32 (reference returns jnp.float32; "bf16" in test label = _any_bf16 input flag).
  const float* x          = (const float*)d_in[0];
  const float* in_proj_w  = (const float*)d_in[1];
  const float* conv_w     = (const float*)d_in[2];
  const float* conv_b     = (const float*)d_in[3];
  const float* dt_bias    = (const float*)d_in[4];
  const float* A_log      = (const float*)d_in[5];
  const float* Dv         = (const float*)d_in[6];
  const float* norm_w     = (const float*)d_in[7];
  const float* out_proj_w = (const float*)d_in[8];
  const float* cls_w      = (const float*)d_in[9];
  const float* cls_b      = (const float*)d_in[10];

  char* ws = (char*)d_ws;
  // workspace layout (total 212,860,928 bytes):
  unsigned short* zxb = (unsigned short*)(ws + 0);            // 137,363,456  bf16 [8192,8384]
  unsigned short* xh  = (unsigned short*)(ws + 137363456);    //  67,108,864  bf16 [8192,4096]
  float*          Bmp = (float*)(ws + 204472320);             //   2,097,152
  float*          Cmp = (float*)(ws + 206569472);             //   2,097,152
  float*          dtv = (float*)(ws + 208666624);             //   2,097,152
  float*          dAv = (float*)(ws + 210763776);             //   2,097,152  -> end 212,860,928
  // aliases (stream-ordered, regions dead at reuse time):
  unsigned short* ynb  = xh;                 // in-place over y (elementwise)
  float*          hbuf = (float*)zxb;        // fp32 [8192,2048] over zxb (dead after norm)

  // 1. fp32 dt path (independent of gemm1)
  dt_kernel<<<512, 256, 0, stream>>>(x, in_proj_w, dt_bias, A_log, dtv, dAv);

  // 2. in-projection GEMM: zxb[8192,8384] = x @ in_proj_w^T  (fp32 in, bf16 out)
  gemm_tiled<false, true><<<dim3(66, 64), 256, 0, stream>>>(x, in_proj_w, zxb,
                                                            MROWS, DINPROJ, DMODEL);

  // 3. conv + silu
  conv_kernel<<<MROWS, 256, 0, stream>>>(zxb, conv_w, conv_b, xh, Bmp, Cmp);

  // 4. selective scan (y in-place over xh)
  scan_kernel<<<256, 256, 0, stream>>>(xh, Bmp, Cmp, dtv, dAv, Dv, xh);

  // 5. gated RMSNorm (in-place bf16 over y)
  norm_kernel<<<MROWS, 256, 0, stream>>>(xh, zxb, norm_w, ynb);

  // 6. out-projection GEMM: hbuf[8192,2048] = ynb @ out_proj_w^T  (bf16 A, fp32 out)
  gemm_tiled<true, false><<<dim3(16, 64), 256, 0, stream>>>(ynb, out_proj_w, hbuf,
                                                            MROWS, DMODEL, DINNER);

  // 7. classifier -> fp32 out
  cls_kernel<<<MROWS, 256, 0, stream>>>(hbuf, cls_w, cls_b, (float*)d_out);
}